// Round 4
// baseline (233.732 us; speedup 1.0000x reference)
//
#include <hip/hip_runtime.h>

// Problem constants: B=16, DIM(C)=512, N=4096, H=8, HD=64, QKV rows = 8*129 = 1032.
#define NB 16
#define NC 512
#define NN 4096
#define NH 8

typedef __attribute__((ext_vector_type(8))) __bf16 bf16x8;
typedef __attribute__((ext_vector_type(4))) float f32x4;

__device__ __forceinline__ unsigned short f2bf(float f) {
    union { float f; unsigned u; } x; x.f = f;
    unsigned r = x.u + 0x7FFF + ((x.u >> 16) & 1);   // round-to-nearest-even
    return (unsigned short)(r >> 16);
}
__device__ __forceinline__ float bits2f(unsigned u) {
    union { unsigned u; float f; } x; x.u = u; return x.f;
}

// K0: repack Wv rows (head-interleaved) + Wp to bf16, gather bv.
__global__ void pack_kernel(const float* __restrict__ Wqkv, const float* __restrict__ bqkv,
                            const float* __restrict__ Wp,
                            unsigned short* __restrict__ Wv_bf, unsigned short* __restrict__ Wp_bf,
                            float* __restrict__ bv) {
    int t = blockIdx.x * 256 + threadIdx.x;          // 0 .. 512*512-1
    int j = t >> 9, c = t & 511;
    int h = j >> 6, d = j & 63;
    Wv_bf[t] = f2bf(Wqkv[((size_t)h * 129 + 65 + d) * 512 + c]);
    Wp_bf[t] = f2bf(Wp[t]);
    if (t < 512) bv[t] = bqkv[(t >> 6) * 129 + 65 + (t & 63)];
}

// K1: fused transpose + q.  Block = (b, 16-n slab) x all 512 c.  35KB LDS -> 4 blocks/CU.
//   x [b][c][n] fp32  ->  xT [b][n][c] bf16
//   q [b][h][n] = sum_c Wq[h,c] * x[b,c,n]   (fp32 exact, bias dropped: softmax shift-inv)
__global__ __launch_bounds__(256) void transpose_q_kernel(
        const float* __restrict__ x, const float* __restrict__ Wqkv,
        unsigned short* __restrict__ xT, float* __restrict__ q) {
    // tile[np][cs]: np = u32-pair index (2 n per u32), cs = XOR-swizzled c.
    __shared__ unsigned int tile[8][520];
    __shared__ float Ws[8][512];
    __shared__ float qw[4][8][16];
    int b = blockIdx.y, n0 = blockIdx.x * 16;
    int t = threadIdx.x;                             // 256
    int lane = t & 63, wv = t >> 6;

    for (int i = t; i < 4096; i += 256)
        Ws[i >> 9][i & 511] = Wqkv[(size_t)(i >> 9) * (129 * 512) + (i & 511)];
    __syncthreads();

    // Phase 1: read x (float4 along n), pack->LDS (swizzled), accumulate q partials.
    int k = t & 3;                                   // n-quad: n = 4k..4k+3
    int r0 = t >> 2;                                 // 0..63
    float accq[8][4];
#pragma unroll
    for (int h = 0; h < 8; h++)
#pragma unroll
        for (int j = 0; j < 4; j++) accq[h][j] = 0.f;
    const float* xp = x + (size_t)b * NC * NN + n0 + 4 * k;
#pragma unroll
    for (int p = 0; p < 8; p++) {
        int c = r0 + 64 * p;
        float4 v = *(const float4*)(xp + (size_t)c * NN);
        unsigned lo = (unsigned)f2bf(v.x) | ((unsigned)f2bf(v.y) << 16);
        unsigned hi = (unsigned)f2bf(v.z) | ((unsigned)f2bf(v.w) << 16);
        int cs = c ^ (2 * ((c >> 5) & 3));           // bank swizzle
        tile[2 * k][cs]     = lo;
        tile[2 * k + 1][cs] = hi;
#pragma unroll
        for (int h = 0; h < 8; h++) {
            float w = Ws[h][c];
            accq[h][0] += w * v.x;
            accq[h][1] += w * v.y;
            accq[h][2] += w * v.z;
            accq[h][3] += w * v.w;
        }
    }
    // q reduce: threads sharing k differ in lane bits 2..5 and wave id.
#pragma unroll
    for (int h = 0; h < 8; h++)
#pragma unroll
        for (int j = 0; j < 4; j++) {
            float a = accq[h][j];
            a += __shfl_xor(a, 4);
            a += __shfl_xor(a, 8);
            a += __shfl_xor(a, 16);
            a += __shfl_xor(a, 32);
            accq[h][j] = a;
        }
    if (lane < 4) {
#pragma unroll
        for (int h = 0; h < 8; h++)
#pragma unroll
            for (int j = 0; j < 4; j++) qw[wv][h][4 * lane + j] = accq[h][j];
    }
    __syncthreads();
    if (t < 128) {
        int h = t >> 4, n = t & 15;
        q[((size_t)b * 8 + h) * NN + n0 + n] =
            qw[0][h][n] + qw[1][h][n] + qw[2][h][n] + qw[3][h][n];
    }

    // Phase 2: transpose out. Each lane composes 2 u32 (c, c+1) -> 256B-contig stores.
    unsigned short* xb = xT + (size_t)b * NN * NC;
#pragma unroll
    for (int it = 0; it < 8; it++) {
        int np = wv * 2 + (it & 1);
        int cw = it >> 1;
        int c = cw * 128 + 2 * lane;
        int m2 = 2 * ((c >> 5) & 3);
        unsigned u0 = tile[np][c ^ m2];
        unsigned u1 = tile[np][(c + 1) ^ m2];
        unsigned rowA = (u0 & 0xFFFFu) | (u1 << 16);
        unsigned rowB = (u0 >> 16) | (u1 & 0xFFFF0000u);
        int n = n0 + 2 * np;
        *(unsigned*)(xb + (size_t)n * NC + c)       = rowA;
        *(unsigned*)(xb + (size_t)(n + 1) * NC + c) = rowB;
    }
}

// K2: softmax over N per (b,h); writes TRANSPOSED scores sT[b][n][h] (fp32).
__global__ void softmax_kernel(const float* __restrict__ q, float* __restrict__ sT) {
    int bh = blockIdx.x;                 // b*8+h
    int b = bh >> 3, h = bh & 7;
    int t = threadIdx.x;                 // 256
    __shared__ float red[8];
    const float* qp = q + (size_t)bh * NN;
    float v[16];
    float mx = -1e30f;
#pragma unroll
    for (int i = 0; i < 16; i++) { v[i] = qp[t + i * 256]; mx = fmaxf(mx, v[i]); }
#pragma unroll
    for (int o = 32; o; o >>= 1) mx = fmaxf(mx, __shfl_xor(mx, o));
    if ((t & 63) == 0) red[t >> 6] = mx;
    __syncthreads();
    mx = fmaxf(fmaxf(red[0], red[1]), fmaxf(red[2], red[3]));
    float s = 0.f;
#pragma unroll
    for (int i = 0; i < 16; i++) { v[i] = __expf(v[i] - mx); s += v[i]; }
#pragma unroll
    for (int o = 32; o; o >>= 1) s += __shfl_xor(s, o);
    __syncthreads();
    if ((t & 63) == 0) red[4 + (t >> 6)] = s;
    __syncthreads();
    float inv = 1.f / (red[4] + red[5] + red[6] + red[7]);
#pragma unroll
    for (int i = 0; i < 16; i++) {
        int n = t + i * 256;
        sT[((size_t)b * NN + n) * 8 + h] = v[i] * inv;
    }
}

// K3: partial xbar[sl64][b][h][c] = sum_{n in 64-slice} sT[b][n][h] * xT[b][n][c]
__global__ void xbar_kernel(const unsigned short* __restrict__ xT, const float* __restrict__ sT,
                            float* __restrict__ xbarP) {
    int b = blockIdx.y, sl = blockIdx.x;                 // 16 slices of 256 n
    int t = threadIdx.x;
    int g = __builtin_amdgcn_readfirstlane(t >> 6);      // wave id (uniform)
    int lane = t & 63;
    int c8 = lane * 8;
    int nbase = sl * 256 + g * 64;
    float acc[8][8];
#pragma unroll
    for (int h = 0; h < 8; h++)
#pragma unroll
        for (int c = 0; c < 8; c++) acc[h][c] = 0.f;
    const unsigned short* xp = xT + ((size_t)b * NN + nbase) * NC + c8;
    const float* sp = sT + ((size_t)b * NN + nbase) * 8;
    for (int i = 0; i < 64; i++) {
        uint4 xv = *(const uint4*)(xp + (size_t)i * NC);
        float xf[8];
        xf[0] = bits2f(xv.x << 16); xf[1] = bits2f(xv.x & 0xFFFF0000u);
        xf[2] = bits2f(xv.y << 16); xf[3] = bits2f(xv.y & 0xFFFF0000u);
        xf[4] = bits2f(xv.z << 16); xf[5] = bits2f(xv.z & 0xFFFF0000u);
        xf[6] = bits2f(xv.w << 16); xf[7] = bits2f(xv.w & 0xFFFF0000u);
#pragma unroll
        for (int h = 0; h < 8; h++) {
            float s = sp[i * 8 + h];
#pragma unroll
            for (int c = 0; c < 8; c++) acc[h][c] += s * xf[c];
        }
    }
#pragma unroll
    for (int h = 0; h < 8; h++) {
        float* dst = xbarP + (((size_t)(sl * 4 + g) * NB + b) * 8 + h) * NC + c8;
        f32x4 lo = {acc[h][0], acc[h][1], acc[h][2], acc[h][3]};
        f32x4 hi = {acc[h][4], acc[h][5], acc[h][6], acc[h][7]};
        *(f32x4*)(dst) = lo;
        *(f32x4*)(dst + 4) = hi;
    }
}

// K4: ctx[b][h*64+d] = Wk[h,d,:].xbar[b,h,:] + bk[h,d]   (sums 64 partial slices)
__global__ void ctx_kernel(const float* __restrict__ xbarP, const float* __restrict__ Wqkv,
                           const float* __restrict__ bqkv, float* __restrict__ ctx) {
    int bh = blockIdx.x; int b = bh >> 3, h = bh & 7;
    int t = threadIdx.x;                                    // 256
    __shared__ float xb[512];
    for (int i = t; i < 512; i += 256) {
        float s = 0.f;
        for (int sl = 0; sl < 64; sl++) s += xbarP[(((size_t)sl * NB + b) * 8 + h) * NC + i];
        xb[i] = s;
    }
    __syncthreads();
    int d = t >> 2, sub = t & 3;
    const float* wk = Wqkv + ((size_t)h * 129 + 1 + d) * 512;
    float acc = 0.f;
    for (int i = sub * 4; i < 512; i += 16) {
        float4 w = *(const float4*)(wk + i);
        acc += w.x * xb[i] + w.y * xb[i + 1] + w.z * xb[i + 2] + w.w * xb[i + 3];
    }
    acc += __shfl_xor(acc, 1);
    acc += __shfl_xor(acc, 2);
    if (sub == 0) ctx[(size_t)b * NC + h * 64 + d] = acc + bqkv[h * 129 + 1 + d];
}

// K5/K6: C[512 x 4096] = A[512x512] * B^T  (B stored as [n][k] bf16 rows), per batch.
// MODE 0: epilogue relu(acc+bv)*ctx -> bf16, written TRANSPOSED mT[b][n][j].
// MODE 1: epilogue acc+bp -> fp32 out[b][o][n].
template <int MODE>
__global__ __launch_bounds__(512) void gemm_kernel(
    const unsigned short* __restrict__ A,     // [512][512] bf16 row-major
    const unsigned short* __restrict__ Bmat,  // [B][4096][512] bf16
    const float* __restrict__ bias,           // bv or bp
    const float* __restrict__ ctx,            // [B][512] (MODE 0)
    unsigned short* __restrict__ mT,          // MODE 0 output
    float* __restrict__ outp)                 // MODE 1 output
{
    __shared__ alignas(16) unsigned short As[256 * 32];   // [m][k]
    __shared__ alignas(16) unsigned short Bs[128 * 32];   // [n][k]
    int b = blockIdx.z;
    int m0 = blockIdx.y * 256, n0 = blockIdx.x * 128;
    int t = threadIdx.x;
    int lane = t & 63;
    int wid = t >> 6;
    int wm = wid >> 1, wn = wid & 1;                      // 4x2 wave grid, 64x64 per wave

    const unsigned short* Bb = Bmat + ((size_t)b * NN + n0) * NC;

    f32x4 acc[4][4];
#pragma unroll
    for (int i = 0; i < 4; i++)
#pragma unroll
        for (int j = 0; j < 4; j++) { f32x4 z = {0.f, 0.f, 0.f, 0.f}; acc[i][j] = z; }

    for (int kk = 0; kk < 512; kk += 32) {
        {
            int u = t, row = u >> 2, kg = u & 3;
            uint4 va = *(const uint4*)(A + (size_t)(m0 + row) * 512 + kk + kg * 8);
            *(uint4*)(As + (size_t)u * 8) = va;
            u = t + 512; row = u >> 2; kg = u & 3;
            uint4 vb = *(const uint4*)(A + (size_t)(m0 + row) * 512 + kk + kg * 8);
            *(uint4*)(As + (size_t)u * 8) = vb;
            u = t; row = u >> 2; kg = u & 3;
            uint4 vc = *(const uint4*)(Bb + (size_t)row * 512 + kk + kg * 8);
            *(uint4*)(Bs + (size_t)u * 8) = vc;
        }
        __syncthreads();
        bf16x8 af[4], bfr[4];
        int koff = (lane >> 4) * 8;
        int arow = wm * 64 + (lane & 15);
        int brow = wn * 64 + (lane & 15);
#pragma unroll
        for (int i = 0; i < 4; i++) af[i]  = *(const bf16x8*)(As + (size_t)(arow + i * 16) * 32 + koff);
#pragma unroll
        for (int j = 0; j < 4; j++) bfr[j] = *(const bf16x8*)(Bs + (size_t)(brow + j * 16) * 32 + koff);
#pragma unroll
        for (int i = 0; i < 4; i++)
#pragma unroll
            for (int j = 0; j < 4; j++)
                acc[i][j] = __builtin_amdgcn_mfma_f32_16x16x32_bf16(af[i], bfr[j], acc[i][j], 0, 0, 0);
        __syncthreads();
    }

    // epilogue; D frag: col = lane&15, row = (lane>>4)*4 + reg
    int g = lane >> 4, col = lane & 15;
#pragma unroll
    for (int i = 0; i < 4; i++) {
        int j0 = m0 + wm * 64 + i * 16 + g * 4;           // 4 consecutive output rows
        if (MODE == 0) {
            float4 bv4 = *(const float4*)(bias + j0);
            float4 cx4 = *(const float4*)(ctx + (size_t)b * NC + j0);
#pragma unroll
            for (int j = 0; j < 4; j++) {
                int n = n0 + wn * 64 + j * 16 + col;
                f32x4 a = acc[i][j];
                unsigned short h0 = f2bf(fmaxf(a[0] + bv4.x, 0.f) * cx4.x);
                unsigned short h1 = f2bf(fmaxf(a[1] + bv4.y, 0.f) * cx4.y);
                unsigned short h2 = f2bf(fmaxf(a[2] + bv4.z, 0.f) * cx4.z);
                unsigned short h3 = f2bf(fmaxf(a[3] + bv4.w, 0.f) * cx4.w);
                uint2 pk;
                pk.x = (unsigned)h0 | ((unsigned)h1 << 16);
                pk.y = (unsigned)h2 | ((unsigned)h3 << 16);
                *(uint2*)(mT + ((size_t)b * NN + n) * NC + j0) = pk;
            }
        } else {
            float4 bp4 = *(const float4*)(bias + j0);
#pragma unroll
            for (int j = 0; j < 4; j++) {
                int n = n0 + wn * 64 + j * 16 + col;
                f32x4 a = acc[i][j];
                float* op = outp + (size_t)b * NC * NN + (size_t)j0 * NN + n;
                op[0]              = a[0] + bp4.x;
                op[NN]             = a[1] + bp4.y;
                op[2 * (size_t)NN] = a[2] + bp4.z;
                op[3 * (size_t)NN] = a[3] + bp4.w;
            }
        }
    }
}

extern "C" void kernel_launch(void* const* d_in, const int* in_sizes, int n_in,
                              void* d_out, int out_size, void* d_ws, size_t ws_size,
                              hipStream_t stream) {
    const float* x    = (const float*)d_in[0];
    const float* Wqkv = (const float*)d_in[1];
    const float* bqkv = (const float*)d_in[2];
    const float* Wp   = (const float*)d_in[3];
    const float* bp   = (const float*)d_in[4];
    float* outp = (float*)d_out;

    // ws layout. mT occupies [0, 64MB). sT/q/xbarP overlap mT's range but are
    // fully consumed (K1..K4) before K5 writes mT. ctx/Wv/Wp/bv live past 64MB.
    char* ws = (char*)d_ws;
    unsigned short* mT = (unsigned short*)ws;                         // 64 MB
    float* sT    = (float*)(ws + 2097152);                            // [2MB,4MB)
    float* q     = (float*)(ws + 4194304);                            // [4MB,6MB)
    float* xbarP = (float*)(ws + 20971520);                           // [20MB,36MB)
    float* ctx   = (float*)(ws + 67108864);                           // 32 KB
    unsigned short* Wv_bf = (unsigned short*)(ws + 67108864 + 32768);            // 512 KB
    unsigned short* Wp_bf = (unsigned short*)(ws + 67108864 + 32768 + 524288);   // 512 KB
    float* bv    = (float*)(ws + 67108864 + 32768 + 1048576);         // 2 KB
    // xT (bf16 transposed x, 64MB) lives in d_out's first half; K6 overwrites all of d_out.
    unsigned short* xT = (unsigned short*)d_out;

    pack_kernel<<<dim3(1024), 256, 0, stream>>>(Wqkv, bqkv, Wp, Wv_bf, Wp_bf, bv);
    transpose_q_kernel<<<dim3(256, 16), 256, 0, stream>>>(x, Wqkv, xT, q);
    softmax_kernel<<<dim3(128), 256, 0, stream>>>(q, sT);
    xbar_kernel<<<dim3(16, 16), 256, 0, stream>>>(xT, sT, xbarP);
    ctx_kernel<<<dim3(128), 256, 0, stream>>>(xbarP, Wqkv, bqkv, ctx);
    gemm_kernel<0><<<dim3(32, 2, 16), 512, 0, stream>>>(Wv_bf, xT, bv, ctx, mT, nullptr);
    gemm_kernel<1><<<dim3(32, 2, 16), 512, 0, stream>>>(Wp_bf, mT, bp, nullptr, nullptr, outp);
}

// Round 5
// 213.284 us; speedup vs baseline: 1.0959x; 1.0959x over previous
//
#include <hip/hip_runtime.h>

// Problem constants: B=16, DIM(C)=512, N=4096, H=8, HD=64, QKV rows = 8*129 = 1032.
#define NB 16
#define NC 512
#define NN 4096
#define NH 8

typedef __attribute__((ext_vector_type(8))) __bf16 bf16x8;
typedef __attribute__((ext_vector_type(4))) float f32x4;

__device__ __forceinline__ unsigned short f2bf(float f) {
    union { float f; unsigned u; } x; x.f = f;
    unsigned r = x.u + 0x7FFF + ((x.u >> 16) & 1);   // round-to-nearest-even
    return (unsigned short)(r >> 16);
}
__device__ __forceinline__ float bits2f(unsigned u) {
    union { unsigned u; float f; } x; x.u = u; return x.f;
}

// async global->LDS 16B per lane; LDS dest must be wave-uniform base (HW adds lane*16).
__device__ __forceinline__ void async16(const void* g, const void* l) {
    __builtin_amdgcn_global_load_lds(
        (const __attribute__((address_space(1))) void*)g,
        (__attribute__((address_space(3))) void*)l, 16, 0, 0);
}

// K0: repack Wv rows (head-interleaved) + Wp to bf16, gather bv.
__global__ void pack_kernel(const float* __restrict__ Wqkv, const float* __restrict__ bqkv,
                            const float* __restrict__ Wp,
                            unsigned short* __restrict__ Wv_bf, unsigned short* __restrict__ Wp_bf,
                            float* __restrict__ bv) {
    int t = blockIdx.x * 256 + threadIdx.x;          // 0 .. 512*512-1
    int j = t >> 9, c = t & 511;
    int h = j >> 6, d = j & 63;
    Wv_bf[t] = f2bf(Wqkv[((size_t)h * 129 + 65 + d) * 512 + c]);
    Wp_bf[t] = f2bf(Wp[t]);
    if (t < 512) bv[t] = bqkv[(t >> 6) * 129 + 65 + (t & 63)];
}

// K1: fused transpose + q.  Block = (b, 32-n slab) x all 512 c.   (exact R2 version)
//   x [b][c][n] fp32  ->  xT [b][n][c] bf16
//   q [b][h][n] = sum_c Wq[h,c] * x[b,c,n]   (fp32 exact, bias dropped: softmax shift-inv)
__global__ __launch_bounds__(256) void transpose_q_kernel(
        const float* __restrict__ x, const float* __restrict__ Wqkv,
        unsigned short* __restrict__ xT, float* __restrict__ q) {
    __shared__ unsigned int tile[512 * 17];          // u32 = 2 packed bf16; pad 17 (coprime 32)
    __shared__ float Ws[8][512];
    __shared__ float qw[4][8][32];
    int b = blockIdx.y, n0 = blockIdx.x * 32;
    int t = threadIdx.x;                             // 256

    for (int i = t; i < 4096; i += 256)
        Ws[i >> 9][i & 511] = Wqkv[(size_t)(i >> 9) * (129 * 512) + (i & 511)];
    __syncthreads();

    // Phase 1: read x (coalesced float4 along n), pack->LDS, accumulate q partials.
    int k = t & 7;                                   // n-quad: n = 4k..4k+3
    int r0 = t >> 3;                                 // 0..31
    float accq[8][4];
#pragma unroll
    for (int h = 0; h < 8; h++)
#pragma unroll
        for (int j = 0; j < 4; j++) accq[h][j] = 0.f;
    const float* xp = x + (size_t)b * NC * NN + n0 + 4 * k;
#pragma unroll 4
    for (int p = 0; p < 16; p++) {
        int c = r0 + 32 * p;
        float4 v = *(const float4*)(xp + (size_t)c * NN);
        unsigned lo = (unsigned)f2bf(v.x) | ((unsigned)f2bf(v.y) << 16);
        unsigned hi = (unsigned)f2bf(v.z) | ((unsigned)f2bf(v.w) << 16);
        tile[c * 17 + 2 * k]     = lo;
        tile[c * 17 + 2 * k + 1] = hi;
#pragma unroll
        for (int h = 0; h < 8; h++) {
            float w = Ws[h][c];
            accq[h][0] += w * v.x;
            accq[h][1] += w * v.y;
            accq[h][2] += w * v.z;
            accq[h][3] += w * v.w;
        }
    }
    // q reduce: lanes sharing k (lane&7) differ in lane bits 3..5 = c-subset -> xor 8/16/32
    int lane = t & 63, wv = t >> 6;
#pragma unroll
    for (int h = 0; h < 8; h++)
#pragma unroll
        for (int j = 0; j < 4; j++) {
            float a = accq[h][j];
            a += __shfl_xor(a, 8);
            a += __shfl_xor(a, 16);
            a += __shfl_xor(a, 32);
            accq[h][j] = a;
        }
    if (lane < 8) {
#pragma unroll
        for (int h = 0; h < 8; h++)
#pragma unroll
            for (int j = 0; j < 4; j++) qw[wv][h][4 * lane + j] = accq[h][j];
    }
    __syncthreads();
    {
        int h = t >> 5, n = t & 31;
        q[((size_t)b * 8 + h) * NN + n0 + n] =
            qw[0][h][n] + qw[1][h][n] + qw[2][h][n] + qw[3][h][n];
    }

    // Phase 2: transpose out. lane = c (conflict-free: stride 17 u32), 128B-contig u16 stores.
    unsigned short* xb = xT + (size_t)b * NN * NC;
    for (int it = wv; it < 128; it += 4) {
        int cw = it >> 4, np = it & 15;
        int c = cw * 64 + lane;
        unsigned u = tile[c * 17 + np];
        int n = n0 + 2 * np;
        xb[(size_t)n * NC + c]       = (unsigned short)(u & 0xFFFFu);
        xb[(size_t)(n + 1) * NC + c] = (unsigned short)(u >> 16);
    }
}

// K2: softmax over N per (b,h); writes TRANSPOSED scores sT[b][n][h] (fp32).
__global__ void softmax_kernel(const float* __restrict__ q, float* __restrict__ sT) {
    int bh = blockIdx.x;                 // b*8+h
    int b = bh >> 3, h = bh & 7;
    int t = threadIdx.x;                 // 256
    __shared__ float red[8];
    const float* qp = q + (size_t)bh * NN;
    float v[16];
    float mx = -1e30f;
#pragma unroll
    for (int i = 0; i < 16; i++) { v[i] = qp[t + i * 256]; mx = fmaxf(mx, v[i]); }
#pragma unroll
    for (int o = 32; o; o >>= 1) mx = fmaxf(mx, __shfl_xor(mx, o));
    if ((t & 63) == 0) red[t >> 6] = mx;
    __syncthreads();
    mx = fmaxf(fmaxf(red[0], red[1]), fmaxf(red[2], red[3]));
    float s = 0.f;
#pragma unroll
    for (int i = 0; i < 16; i++) { v[i] = __expf(v[i] - mx); s += v[i]; }
#pragma unroll
    for (int o = 32; o; o >>= 1) s += __shfl_xor(s, o);
    __syncthreads();
    if ((t & 63) == 0) red[4 + (t >> 6)] = s;
    __syncthreads();
    float inv = 1.f / (red[4] + red[5] + red[6] + red[7]);
#pragma unroll
    for (int i = 0; i < 16; i++) {
        int n = t + i * 256;
        sT[((size_t)b * NN + n) * 8 + h] = v[i] * inv;
    }
}

// K3: partial xbar[sl64][b][h][c] = sum_{n in 64-slice} sT[b][n][h] * xT[b][n][c]
__global__ void xbar_kernel(const unsigned short* __restrict__ xT, const float* __restrict__ sT,
                            float* __restrict__ xbarP) {
    int b = blockIdx.y, sl = blockIdx.x;                 // 16 slices of 256 n
    int t = threadIdx.x;
    int g = __builtin_amdgcn_readfirstlane(t >> 6);      // wave id (uniform)
    int lane = t & 63;
    int c8 = lane * 8;
    int nbase = sl * 256 + g * 64;
    float acc[8][8];
#pragma unroll
    for (int h = 0; h < 8; h++)
#pragma unroll
        for (int c = 0; c < 8; c++) acc[h][c] = 0.f;
    const unsigned short* xp = xT + ((size_t)b * NN + nbase) * NC + c8;
    const float* sp = sT + ((size_t)b * NN + nbase) * 8;
    for (int i = 0; i < 64; i++) {
        uint4 xv = *(const uint4*)(xp + (size_t)i * NC);
        float xf[8];
        xf[0] = bits2f(xv.x << 16); xf[1] = bits2f(xv.x & 0xFFFF0000u);
        xf[2] = bits2f(xv.y << 16); xf[3] = bits2f(xv.y & 0xFFFF0000u);
        xf[4] = bits2f(xv.z << 16); xf[5] = bits2f(xv.z & 0xFFFF0000u);
        xf[6] = bits2f(xv.w << 16); xf[7] = bits2f(xv.w & 0xFFFF0000u);
#pragma unroll
        for (int h = 0; h < 8; h++) {
            float s = sp[i * 8 + h];
#pragma unroll
            for (int c = 0; c < 8; c++) acc[h][c] += s * xf[c];
        }
    }
#pragma unroll
    for (int h = 0; h < 8; h++) {
        float* dst = xbarP + (((size_t)(sl * 4 + g) * NB + b) * 8 + h) * NC + c8;
        f32x4 lo = {acc[h][0], acc[h][1], acc[h][2], acc[h][3]};
        f32x4 hi = {acc[h][4], acc[h][5], acc[h][6], acc[h][7]};
        *(f32x4*)(dst) = lo;
        *(f32x4*)(dst + 4) = hi;
    }
}

// K4: ctx[b][h*64+d] = Wk[h,d,:].xbar[b,h,:] + bk[h,d]   (sums 64 partial slices)
__global__ void ctx_kernel(const float* __restrict__ xbarP, const float* __restrict__ Wqkv,
                           const float* __restrict__ bqkv, float* __restrict__ ctx) {
    int bh = blockIdx.x; int b = bh >> 3, h = bh & 7;
    int t = threadIdx.x;                                    // 256
    __shared__ float xb[512];
    for (int i = t; i < 512; i += 256) {
        float s = 0.f;
        for (int sl = 0; sl < 64; sl++) s += xbarP[(((size_t)sl * NB + b) * 8 + h) * NC + i];
        xb[i] = s;
    }
    __syncthreads();
    int d = t >> 2, sub = t & 3;
    const float* wk = Wqkv + ((size_t)h * 129 + 1 + d) * 512;
    float acc = 0.f;
    for (int i = sub * 4; i < 512; i += 16) {
        float4 w = *(const float4*)(wk + i);
        acc += w.x * xb[i] + w.y * xb[i + 1] + w.z * xb[i + 2] + w.w * xb[i + 3];
    }
    acc += __shfl_xor(acc, 1);
    acc += __shfl_xor(acc, 2);
    if (sub == 0) ctx[(size_t)b * NC + h * 64 + d] = acc + bqkv[h * 129 + 1 + d];
}

// K5/K6: C[512 x 4096] = A[512x512] * B^T  (B stored as [n][k] bf16 rows), per batch.
// Staging via global_load_lds width=16 (m97 pattern): per wave, 3 async 1KB chunks.
// MODE 0: epilogue relu(acc+bv)*ctx -> bf16, written TRANSPOSED mT[b][n][j].
// MODE 1: epilogue acc+bp -> fp32 out[b][o][n].
template <int MODE>
__global__ __launch_bounds__(512) void gemm_kernel(
    const unsigned short* __restrict__ A,     // [512][512] bf16 row-major
    const unsigned short* __restrict__ Bmat,  // [B][4096][512] bf16
    const float* __restrict__ bias,           // bv or bp
    const float* __restrict__ ctx,            // [B][512] (MODE 0)
    unsigned short* __restrict__ mT,          // MODE 0 output
    float* __restrict__ outp)                 // MODE 1 output
{
    __shared__ alignas(16) unsigned short As[256 * 32];   // [m][k] linear (async dest)
    __shared__ alignas(16) unsigned short Bs[128 * 32];   // [n][k] linear (async dest)
    int b = blockIdx.z;
    int m0 = blockIdx.y * 256, n0 = blockIdx.x * 128;
    int t = threadIdx.x;
    int lane = t & 63;
    int wid = t >> 6;                                     // 8 waves
    int wm = wid >> 1, wn = wid & 1;                      // 4x2 wave grid, 64x64 per wave

    const unsigned short* Bb = Bmat + ((size_t)b * NN + n0) * NC;

    // per-lane source offsets for async staging (16B each; dest = wave base + lane*16)
    int srow = lane >> 2, sc8 = (lane & 3) * 8;

    f32x4 acc[4][4];
#pragma unroll
    for (int i = 0; i < 4; i++)
#pragma unroll
        for (int j = 0; j < 4; j++) { f32x4 z = {0.f, 0.f, 0.f, 0.f}; acc[i][j] = z; }

    for (int kk = 0; kk < 512; kk += 32) {
        // A rows [wid*32, wid*32+32): two 1KB chunks; B rows [wid*16, wid*16+16): one.
        async16(A + (size_t)(m0 + wid * 32 + srow) * 512 + kk + sc8,      As + wid * 1024);
        async16(A + (size_t)(m0 + wid * 32 + 16 + srow) * 512 + kk + sc8, As + wid * 1024 + 512);
        async16(Bb + (size_t)(wid * 16 + srow) * 512 + kk + sc8,          Bs + wid * 512);
        __syncthreads();                                  // drains vmcnt before barrier
        bf16x8 af[4], bfr[4];
        int koff = (lane >> 4) * 8;
        int arow = wm * 64 + (lane & 15);
        int brow = wn * 64 + (lane & 15);
#pragma unroll
        for (int i = 0; i < 4; i++) af[i]  = *(const bf16x8*)(As + (size_t)(arow + i * 16) * 32 + koff);
#pragma unroll
        for (int j = 0; j < 4; j++) bfr[j] = *(const bf16x8*)(Bs + (size_t)(brow + j * 16) * 32 + koff);
#pragma unroll
        for (int i = 0; i < 4; i++)
#pragma unroll
            for (int j = 0; j < 4; j++)
                acc[i][j] = __builtin_amdgcn_mfma_f32_16x16x32_bf16(af[i], bfr[j], acc[i][j], 0, 0, 0);
        __syncthreads();
    }

    // epilogue; D frag: col = lane&15, row = (lane>>4)*4 + reg
    int g = lane >> 4, col = lane & 15;
#pragma unroll
    for (int i = 0; i < 4; i++) {
        int j0 = m0 + wm * 64 + i * 16 + g * 4;           // 4 consecutive output rows
        if (MODE == 0) {
            float4 bv4 = *(const float4*)(bias + j0);
            float4 cx4 = *(const float4*)(ctx + (size_t)b * NC + j0);
#pragma unroll
            for (int j = 0; j < 4; j++) {
                int n = n0 + wn * 64 + j * 16 + col;
                f32x4 a = acc[i][j];
                unsigned short h0 = f2bf(fmaxf(a[0] + bv4.x, 0.f) * cx4.x);
                unsigned short h1 = f2bf(fmaxf(a[1] + bv4.y, 0.f) * cx4.y);
                unsigned short h2 = f2bf(fmaxf(a[2] + bv4.z, 0.f) * cx4.z);
                unsigned short h3 = f2bf(fmaxf(a[3] + bv4.w, 0.f) * cx4.w);
                uint2 pk;
                pk.x = (unsigned)h0 | ((unsigned)h1 << 16);
                pk.y = (unsigned)h2 | ((unsigned)h3 << 16);
                *(uint2*)(mT + ((size_t)b * NN + n) * NC + j0) = pk;
            }
        } else {
            float4 bp4 = *(const float4*)(bias + j0);
#pragma unroll
            for (int j = 0; j < 4; j++) {
                int n = n0 + wn * 64 + j * 16 + col;
                f32x4 a = acc[i][j];
                float* op = outp + (size_t)b * NC * NN + (size_t)j0 * NN + n;
                op[0]              = a[0] + bp4.x;
                op[NN]             = a[1] + bp4.y;
                op[2 * (size_t)NN] = a[2] + bp4.z;
                op[3 * (size_t)NN] = a[3] + bp4.w;
            }
        }
    }
}

extern "C" void kernel_launch(void* const* d_in, const int* in_sizes, int n_in,
                              void* d_out, int out_size, void* d_ws, size_t ws_size,
                              hipStream_t stream) {
    const float* x    = (const float*)d_in[0];
    const float* Wqkv = (const float*)d_in[1];
    const float* bqkv = (const float*)d_in[2];
    const float* Wp   = (const float*)d_in[3];
    const float* bp   = (const float*)d_in[4];
    float* outp = (float*)d_out;

    // ws layout. mT occupies [0, 64MB). sT/q/xbarP overlap mT's range but are
    // fully consumed (K1..K4) before K5 writes mT. ctx/Wv/Wp/bv live past 64MB.
    char* ws = (char*)d_ws;
    unsigned short* mT = (unsigned short*)ws;                         // 64 MB
    float* sT    = (float*)(ws + 2097152);                            // [2MB,4MB)
    float* q     = (float*)(ws + 4194304);                            // [4MB,6MB)
    float* xbarP = (float*)(ws + 20971520);                           // [20MB,36MB)
    float* ctx   = (float*)(ws + 67108864);                           // 32 KB
    unsigned short* Wv_bf = (unsigned short*)(ws + 67108864 + 32768);            // 512 KB
    unsigned short* Wp_bf = (unsigned short*)(ws + 67108864 + 32768 + 524288);   // 512 KB
    float* bv    = (float*)(ws + 67108864 + 32768 + 1048576);         // 2 KB
    // xT (bf16 transposed x, 64MB) lives in d_out's first half; K6 overwrites all of d_out.
    unsigned short* xT = (unsigned short*)d_out;

    pack_kernel<<<dim3(1024), 256, 0, stream>>>(Wqkv, bqkv, Wp, Wv_bf, Wp_bf, bv);
    transpose_q_kernel<<<dim3(128, 16), 256, 0, stream>>>(x, Wqkv, xT, q);
    softmax_kernel<<<dim3(128), 256, 0, stream>>>(q, sT);
    xbar_kernel<<<dim3(16, 16), 256, 0, stream>>>(xT, sT, xbarP);
    ctx_kernel<<<dim3(128), 256, 0, stream>>>(xbarP, Wqkv, bqkv, ctx);
    gemm_kernel<0><<<dim3(32, 2, 16), 512, 0, stream>>>(Wv_bf, xT, bv, ctx, mT, nullptr);
    gemm_kernel<1><<<dim3(32, 2, 16), 512, 0, stream>>>(Wp_bf, mT, bp, nullptr, nullptr, outp);
}